// Round 13
// baseline (419.341 us; speedup 1.0000x reference)
//
#include <hip/hip_runtime.h>
#include <hip/hip_bf16.h>

// Dual-stage topic attention. f32 I/O, bf16 intermediates.
//   segmean+cvt: Mx = segmean(x), Xb = bf16(x)  (one x read, fused)
//   Wb* = bf16(W*)  (weights-only cvt dispatch)
//   Mb = Mx + Mx@Wc^T + bc; Mq = Mb@Wq^T
//   [Q|K|V] = Xb @ [Wq|Wk|Wv]^T + bias
//   T = Q + Mq[seg] (on the fly)
//   VT = attn(T,K,V) -> d_out[0:half) ; CTX = attn(Q,T,VT) -> K slot
//   out = CTX @ Wo^T + bo (f32)
// r13: glds staging + XOR SOURCE-PERMUTE — glds dest is fixed lane*16, so the
// bank swizzle is created by permuting which global chunk each lane fetches
// (slot s of row r <- chunk s^((r>>1)&3)); fragment reads at slot
// quad^((l15>>1)&3) reproduce r11's measured-0-conflict pattern. Coalescing
// unaffected (same 64B segments per 4-lane group).

typedef __bf16 bf16_t;
typedef __bf16 bf16x8 __attribute__((ext_vector_type(8)));
typedef __bf16 bf16x4 __attribute__((ext_vector_type(4)));
typedef float f32x4 __attribute__((ext_vector_type(4)));

#define B_ 32
#define N_ 512
#define D_ 768
#define H_ 12
#define HD_ 64
#define K_ 8
#define ND_ (N_ * D_)   // 393216

typedef __attribute__((address_space(1))) unsigned int as1_u32;
typedef __attribute__((address_space(3))) unsigned int as3_u32;

__device__ __forceinline__ void glds16(const void* g, void* l) {
  // async global->LDS, 16B/lane; LDS dest = wave-uniform base + lane*16
  __builtin_amdgcn_global_load_lds((as1_u32*)g, (as3_u32*)l, 16, 0, 0);
}

__device__ __forceinline__ f32x4 mfma16(bf16x8 a, bf16x8 b, f32x4 c) {
  return __builtin_amdgcn_mfma_f32_16x16x32_bf16(a, b, c, 0, 0, 0);
}

__device__ __forceinline__ bf16x8 addv8(bf16x8 a, bf16x8 b) {
  bf16x8 o;
#pragma unroll
  for (int j = 0; j < 8; ++j) o[j] = (bf16_t)((float)a[j] + (float)b[j]);
  return o;
}

// tid int32 or int64; int64 => word[1] (high half of elem0) == 0 (values 1..8).
__device__ __forceinline__ int seg_of(const int* tid, int b) {
  const bool is64 = (tid[1] == 0);
  int v = is64 ? (int)((const long long*)tid)[b] : tid[b];
  return v - 1;
}

// Weights-only f32->bf16 (5 matrices x 288 blocks).
__global__ __launch_bounds__(256) void k_cvt_w(
    const float* __restrict__ Wq, const float* __restrict__ Wk,
    const float* __restrict__ Wv, const float* __restrict__ Wc,
    const float* __restrict__ Wo, bf16_t* __restrict__ Wqb,
    bf16_t* __restrict__ Wkb, bf16_t* __restrict__ Wvb,
    bf16_t* __restrict__ Wcb, bf16_t* __restrict__ Wob) {
  const int wi = blockIdx.x / 288;
  const int bid = blockIdx.x % 288;
  const float* in = wi == 0 ? Wq : wi == 1 ? Wk : wi == 2 ? Wv : wi == 3 ? Wc
                                                                         : Wo;
  bf16_t* out = wi == 0 ? Wqb : wi == 1 ? Wkb : wi == 2 ? Wvb : wi == 3 ? Wcb
                                                                        : Wob;
  const size_t i = ((size_t)bid * 256 + threadIdx.x) * 8;
  f32x4 a = *(const f32x4*)(in + i);
  f32x4 b = *(const f32x4*)(in + i + 4);
  bf16x8 o;
#pragma unroll
  for (int j = 0; j < 4; ++j) { o[j] = (bf16_t)a[j]; o[4 + j] = (bf16_t)b[j]; }
  *(bf16x8*)(out + i) = o;
}

// ---------------------------------------------------------------------------
// GEMM core (pure bf16): C[128x128] = A[128xK] * B^T[128xK], K=768, BK=32.
// Async glds staging + XOR source-permute, double-buffered, one barrier/iter.
// Thread t = slot (t&3) of row (t>>2): fetches global chunk
// (t&3)^(((t>>2)>>1)&3); frag reads use slot quad^((l15>>1)&3).
// ---------------------------------------------------------------------------
__device__ __forceinline__ void gemm_core(const bf16_t* __restrict__ A,
                                          const bf16_t* __restrict__ Bw,
                                          char* smem, f32x4 (&acc)[4][4]) {
  const int t = threadIdx.x;
  const int lane = t & 63, w = t >> 6;
  const int quad = lane >> 4, l15 = lane & 15;
  const int r0 = t >> 2;                       // staging row; +64 for 2nd half
  const int kc = (t & 3) ^ ((r0 >> 1) & 3);    // source chunk (XOR permute)
  const int c0e = kc * 8;                      // element offset within BK
  const int kcr = quad ^ ((l15 >> 1) & 3);     // swizzled read slot
  const int wbase = w * 1024;                  // wave-uniform LDS base
  const int mRow = (w >> 1) * 64, nCol = (w & 1) * 64;

  const bf16_t* ga0 = A + (size_t)r0 * D_ + c0e;
  const bf16_t* ga1 = A + (size_t)(r0 + 64) * D_ + c0e;  // same key: (+64>>1)&3==0
  const bf16_t* gb0 = Bw + (size_t)r0 * D_ + c0e;
  const bf16_t* gb1 = Bw + (size_t)(r0 + 64) * D_ + c0e;

  glds16(ga0, smem + wbase);
  glds16(ga1, smem + 4096 + wbase);
  glds16(gb0, smem + 8192 + wbase);
  glds16(gb1, smem + 12288 + wbase);

  for (int kb = 0; kb < 24; ++kb) {
    __syncthreads();  // vmcnt(0) drain: iter-kb glds complete; prev reads done
    char* cur = smem + (kb & 1) * 16384;
    char* nxt = smem + ((kb + 1) & 1) * 16384;
    if (kb < 23) {  // async-stage next slice; in flight during MFMA below
      const int ko = (kb + 1) * 32;
      glds16(ga0 + ko, nxt + wbase);
      glds16(ga1 + ko, nxt + 4096 + wbase);
      glds16(gb0 + ko, nxt + 8192 + wbase);
      glds16(gb1 + ko, nxt + 12288 + wbase);
    }
    bf16x8 af[4], bfr[4];
#pragma unroll
    for (int mt = 0; mt < 4; ++mt)
      af[mt] = *(const bf16x8*)(cur + (mRow + mt * 16 + l15) * 64 + kcr * 16);
#pragma unroll
    for (int nt = 0; nt < 4; ++nt)
      bfr[nt] = *(const bf16x8*)(cur + 8192 + (nCol + nt * 16 + l15) * 64 +
                                 kcr * 16);
#pragma unroll
    for (int mt = 0; mt < 4; ++mt)
#pragma unroll
      for (int nt = 0; nt < 4; ++nt)
        acc[mt][nt] = mfma16(af[mt], bfr[nt], acc[mt][nt]);
  }
}

__device__ __forceinline__ void zero_acc(f32x4 (&acc)[4][4]) {
  const f32x4 z = {0.f, 0.f, 0.f, 0.f};
#pragma unroll
  for (int a = 0; a < 4; ++a)
#pragma unroll
    for (int b = 0; b < 4; ++b) acc[a][b] = z;
}

// Fused QKV GEMM (bf16 in/out). grid = 2304 flat, XCD-swizzled.
__global__ __launch_bounds__(256) void k_gemm_qkv(
    const bf16_t* __restrict__ X, const bf16_t* __restrict__ Wq,
    const bf16_t* __restrict__ Wk, const bf16_t* __restrict__ Wv,
    const float* __restrict__ bq, const float* __restrict__ bk,
    const float* __restrict__ bv, bf16_t* __restrict__ Q,
    bf16_t* __restrict__ Kb, bf16_t* __restrict__ V) {
  __shared__ alignas(16) char smem[32768];
  const int bid = blockIdx.x;
  const int xcd = bid & 7, i = bid >> 3;
  const int tile = i % 18, rowblk = (i / 18) * 8 + xcd;
  const int wsel = tile / 6, nb = tile % 6;
  const bf16_t* W = wsel == 0 ? Wq : wsel == 1 ? Wk : Wv;
  const float* bias = wsel == 0 ? bq : wsel == 1 ? bk : bv;
  bf16_t* Out = wsel == 0 ? Q : wsel == 1 ? Kb : V;

  f32x4 acc[4][4];
  zero_acc(acc);
  gemm_core(X + (size_t)rowblk * 128 * D_, W + (size_t)nb * 128 * D_, smem,
            acc);

  const int lane = threadIdx.x & 63, w = threadIdx.x >> 6;
  const int quad = lane >> 4, l15 = lane & 15;
  const int mbase = rowblk * 128 + (w >> 1) * 64;
  const int nbase = nb * 128 + (w & 1) * 64;
#pragma unroll
  for (int nt = 0; nt < 4; ++nt) {
    const int col = nbase + nt * 16 + l15;
    const float bb = bias[col];
#pragma unroll
    for (int mt = 0; mt < 4; ++mt)
#pragma unroll
      for (int r = 0; r < 4; ++r) {
        const int row = mbase + mt * 16 + quad * 4 + r;
        Out[(size_t)row * D_ + col] = (bf16_t)(acc[mt][nt][r] + bb);
      }
  }
}

// Plain GEMM: Out[Mx768] = A(bf16) @ W(bf16)^T (+bias f32) (+addA bf16).
__global__ __launch_bounds__(256) void k_gemm_plain(
    const bf16_t* __restrict__ A, const bf16_t* __restrict__ W,
    const float* __restrict__ bias, const bf16_t* __restrict__ addA,
    void* __restrict__ Out, int outF32, int swz) {
  __shared__ alignas(16) char smem[32768];
  int mblk, nblk;
  if (swz) {
    const int bid = blockIdx.x;
    const int xcd = bid & 7, i = bid >> 3;
    nblk = i % 6;
    mblk = (i / 6) * 8 + xcd;
  } else {
    mblk = blockIdx.x;
    nblk = blockIdx.y;
  }
  f32x4 acc[4][4];
  zero_acc(acc);
  gemm_core(A + (size_t)mblk * 128 * D_, W + (size_t)nblk * 128 * D_, smem,
            acc);
  const int lane = threadIdx.x & 63, w = threadIdx.x >> 6;
  const int quad = lane >> 4, l15 = lane & 15;
  const int mbase = mblk * 128 + (w >> 1) * 64;
  const int nbase = nblk * 128 + (w & 1) * 64;
#pragma unroll
  for (int nt = 0; nt < 4; ++nt) {
    const int col = nbase + nt * 16 + l15;
    const float bb = bias ? bias[col] : 0.f;
#pragma unroll
    for (int mt = 0; mt < 4; ++mt)
#pragma unroll
      for (int r = 0; r < 4; ++r) {
        const int row = mbase + mt * 16 + quad * 4 + r;
        float v = acc[mt][nt][r] + bb;
        if (addA) v += (float)addA[(size_t)row * D_ + col];
        const size_t oi = (size_t)row * D_ + col;
        if (outF32) ((float*)Out)[oi] = v;
        else ((bf16_t*)Out)[oi] = (bf16_t)v;
      }
  }
}

// Fused: segment-mean of x AND Xb = bf16(x) — one pass over x.
__global__ __launch_bounds__(256) void k_segmean_cvt(
    const float* __restrict__ X, const int* __restrict__ tid,
    bf16_t* __restrict__ M, bf16_t* __restrict__ Xb) {
  const size_t i = ((size_t)blockIdx.x * 256 + threadIdx.x) * 8;
  float acc[K_][8];
  float cnt[K_];
#pragma unroll
  for (int k = 0; k < K_; ++k) {
    cnt[k] = 0.f;
#pragma unroll
    for (int j = 0; j < 8; ++j) acc[k][j] = 0.f;
  }
  const bool is64 = (tid[1] == 0);
  for (int b = 0; b < B_; ++b) {
    const int s = (is64 ? (int)((const long long*)tid)[b] : tid[b]) - 1;
    const float* p = X + (size_t)b * ND_ + i;
    f32x4 y0 = *(const f32x4*)p;
    f32x4 y1 = *(const f32x4*)(p + 4);
    bf16x8 xb;
#pragma unroll
    for (int j = 0; j < 4; ++j) {
      xb[j] = (bf16_t)y0[j];
      xb[4 + j] = (bf16_t)y1[j];
    }
    *(bf16x8*)(Xb + (size_t)b * ND_ + i) = xb;
#pragma unroll
    for (int k = 0; k < K_; ++k) {
      const float msk = (s == k) ? 1.f : 0.f;
      cnt[k] += msk;
#pragma unroll
      for (int j = 0; j < 4; ++j) {
        acc[k][j] += msk * y0[j];
        acc[k][4 + j] += msk * y1[j];
      }
    }
  }
#pragma unroll
  for (int k = 0; k < K_; ++k) {
    const float inv = 1.f / fmaxf(cnt[k], 1.f);
    bf16x8 o;
#pragma unroll
    for (int j = 0; j < 8; ++j) o[j] = (bf16_t)(acc[k][j] * inv);
    *(bf16x8*)(M + (size_t)k * ND_ + i) = o;
  }
}

// ---------------------------------------------------------------------------
// Flash attention per (b,h): Out = softmax(Q' @ K'^T / 8) @ V  (EXACT r11/r12)
// ---------------------------------------------------------------------------
__global__ __launch_bounds__(256) void k_attn(const bf16_t* __restrict__ Qp,
                                              const bf16_t* __restrict__ Kp,
                                              const bf16_t* __restrict__ Vp,
                                              const bf16_t* __restrict__ Madd,
                                              const int* __restrict__ tid,
                                              bf16_t* __restrict__ Op,
                                              int addq) {
  __shared__ alignas(16) __bf16 Kt[64][72];
  __shared__ alignas(16) __bf16 Vt[64][72];
  __shared__ alignas(16) __bf16 Pl[4][32][72];

  const int lane = threadIdx.x & 63, w = threadIdx.x >> 6;
  const int quad = lane >> 4, l15 = lane & 15;
  const int b = blockIdx.y / H_, h = blockIdx.y % H_;
  const int q0 = blockIdx.x * 128 + w * 32;
  const size_t base = (size_t)b * ND_ + h * HD_;
  const float C = 0.18033688011112042f;  // log2(e) / sqrt(HD)
  const int sg = seg_of(tid, b);
  const bf16_t* Mh = Madd + (size_t)sg * ND_ + h * HD_;

  bf16x8 aq[2][2];
#pragma unroll
  for (int mt = 0; mt < 2; ++mt)
#pragma unroll
    for (int ks = 0; ks < 2; ++ks) {
      const size_t off = (size_t)(q0 + mt * 16 + l15) * D_ + ks * 32 + quad * 8;
      bf16x8 q = *(const bf16x8*)(Qp + base + off);
      if (addq == 1) q = addv8(q, *(const bf16x8*)(Mh + off));
      aq[mt][ks] = q;
    }

  f32x4 O[2][4];
  float lacc[2][4];
  {
    const f32x4 z = {0.f, 0.f, 0.f, 0.f};
#pragma unroll
    for (int mt = 0; mt < 2; ++mt)
#pragma unroll
      for (int nt = 0; nt < 4; ++nt) O[mt][nt] = z;
#pragma unroll
    for (int mt = 0; mt < 2; ++mt)
#pragma unroll
      for (int r = 0; r < 4; ++r) lacc[mt][r] = 0.f;
  }

  const int sr = threadIdx.x >> 2, sc = threadIdx.x & 3;
  const int sig_sr = ((sr & 15) << 2) | (sr >> 4);  // sigma-permuted V column

  bf16x8 kr[2], vr[2];
#pragma unroll
  for (int half = 0; half < 2; ++half) {
    const int cc = sc + half * 4;
    const size_t off = (size_t)sr * D_ + cc * 8;
    bf16x8 kv = *(const bf16x8*)(Kp + base + off);
    if (addq == 2) kv = addv8(kv, *(const bf16x8*)(Mh + off));
    kr[half] = kv;
    vr[half] = *(const bf16x8*)(Vp + base + off);
  }

  for (int c0 = 0; c0 < N_; c0 += 64) {
    __syncthreads();
#pragma unroll
    for (int half = 0; half < 2; ++half) {
      const int cc = sc + half * 4;
      *(bf16x8*)(&Kt[sr][cc * 8]) = kr[half];
#pragma unroll
      for (int j = 0; j < 8; ++j) Vt[cc * 8 + j][sig_sr] = vr[half][j];
    }
    __syncthreads();

    if (c0 + 64 < N_) {
#pragma unroll
      for (int half = 0; half < 2; ++half) {
        const int cc = sc + half * 4;
        const size_t off = (size_t)(c0 + 64 + sr) * D_ + cc * 8;
        bf16x8 kv = *(const bf16x8*)(Kp + base + off);
        if (addq == 2) kv = addv8(kv, *(const bf16x8*)(Mh + off));
        kr[half] = kv;
        vr[half] = *(const bf16x8*)(Vp + base + off);
      }
    }

    f32x4 S[2][4];
    {
      const f32x4 z = {0.f, 0.f, 0.f, 0.f};
#pragma unroll
      for (int mt = 0; mt < 2; ++mt)
#pragma unroll
        for (int nt = 0; nt < 4; ++nt) S[mt][nt] = z;
    }
#pragma unroll
    for (int ks = 0; ks < 2; ++ks) {
      bf16x8 bk[4];
#pragma unroll
      for (int nt = 0; nt < 4; ++nt)
        bk[nt] = *(const bf16x8*)(&Kt[nt * 16 + l15][ks * 32 + quad * 8]);
#pragma unroll
      for (int mt = 0; mt < 2; ++mt)
#pragma unroll
        for (int nt = 0; nt < 4; ++nt)
          S[mt][nt] = mfma16(aq[mt][ks], bk[nt], S[mt][nt]);
    }

#pragma unroll
    for (int mt = 0; mt < 2; ++mt)
#pragma unroll
      for (int r = 0; r < 4; ++r) {
        bf16x4 pk;
#pragma unroll
        for (int nt = 0; nt < 4; ++nt) {
          const float p = exp2f(S[mt][nt][r] * C);
          lacc[mt][r] += p;
          pk[nt] = (bf16_t)p;
        }
        *(bf16x4*)(&Pl[w][mt * 16 + quad * 4 + r][l15 * 4]) = pk;
      }

#pragma unroll
    for (int ks2 = 0; ks2 < 2; ++ks2) {
      bf16x8 ap[2], bv[4];
#pragma unroll
      for (int mt = 0; mt < 2; ++mt)
        ap[mt] = *(const bf16x8*)(&Pl[w][mt * 16 + l15][ks2 * 32 + quad * 8]);
#pragma unroll
      for (int nt2 = 0; nt2 < 4; ++nt2)
        bv[nt2] = *(const bf16x8*)(&Vt[nt2 * 16 + l15][ks2 * 32 + quad * 8]);
#pragma unroll
      for (int mt = 0; mt < 2; ++mt)
#pragma unroll
        for (int nt2 = 0; nt2 < 4; ++nt2)
          O[mt][nt2] = mfma16(ap[mt], bv[nt2], O[mt][nt2]);
    }
  }

#pragma unroll
  for (int mt = 0; mt < 2; ++mt)
#pragma unroll
    for (int r = 0; r < 4; ++r) {
      float l = lacc[mt][r];
#pragma unroll
      for (int d = 1; d < 16; d <<= 1) l += __shfl_xor(l, d);
      const float inv = 1.f / l;
      const size_t row = base + (size_t)(q0 + mt * 16 + quad * 4 + r) * D_;
#pragma unroll
      for (int nt2 = 0; nt2 < 4; ++nt2)
        Op[row + nt2 * 16 + l15] = (bf16_t)(O[mt][nt2][r] * inv);
    }
}

// Fallback: zero d_out (f32 extent). Fingerprint: absmax == max|ref|.
__global__ __launch_bounds__(256) void k_zero(float* __restrict__ out) {
  const size_t i = ((size_t)blockIdx.x * 256 + threadIdx.x) * 8;
  f32x4 z = {0.f, 0.f, 0.f, 0.f};
  *(f32x4*)(out + i) = z;
  *(f32x4*)(out + i + 4) = z;
}

// ---------------------------------------------------------------------------
extern "C" void kernel_launch(void* const* d_in, const int* in_sizes, int n_in,
                              void* d_out, int out_size, void* d_ws,
                              size_t ws_size, hipStream_t stream) {
  const float* x  = (const float*)d_in[0];
  const int*  tid = (const int*)d_in[1];
  const float* Wq = (const float*)d_in[2];
  const float* bq = (const float*)d_in[3];
  const float* Wk = (const float*)d_in[4];
  const float* bk = (const float*)d_in[5];
  const float* Wv = (const float*)d_in[6];
  const float* bv = (const float*)d_in[7];
  const float* Wo = (const float*)d_in[8];
  const float* bo = (const float*)d_in[9];
  const float* Wc = (const float*)d_in[10];
  const float* bc = (const float*)d_in[11];

  const size_t SZ  = (size_t)B_ * ND_ * sizeof(bf16_t);   // 25165824
  const size_t MSZ = (size_t)K_ * ND_ * sizeof(bf16_t);   // 6291456
  const size_t WSZ = (size_t)D_ * D_ * sizeof(bf16_t);    // 1179648
  if (ws_size < 3 * SZ + MSZ + 5 * WSZ) {  // diagnosable fallback
    k_zero<<<6144, 256, 0, stream>>>((float*)d_out);
    return;
  }

  char* ws = (char*)d_ws;
  bf16_t* Qb  = (bf16_t*)(ws);
  bf16_t* Kb  = (bf16_t*)(ws + SZ);
  bf16_t* Vb  = (bf16_t*)(ws + 2 * SZ);
  bf16_t* Mq  = (bf16_t*)(ws + 3 * SZ);
  bf16_t* Wqb = (bf16_t*)(ws + 3 * SZ + MSZ);
  bf16_t* Wkb = (bf16_t*)(ws + 3 * SZ + MSZ + WSZ);
  bf16_t* Wvb = (bf16_t*)(ws + 3 * SZ + MSZ + 2 * WSZ);
  bf16_t* Wcb = (bf16_t*)(ws + 3 * SZ + MSZ + 3 * WSZ);
  bf16_t* Wob = (bf16_t*)(ws + 3 * SZ + MSZ + 4 * WSZ);
  bf16_t* Mx = Qb;              // transient, dead before QKV writes Q
  bf16_t* Mb = Kb;              // transient, dead before QKV writes K
  bf16_t* VT = (bf16_t*)d_out;  // bf16 scratch: first half of d_out
  bf16_t* Xb = (bf16_t*)d_out + (size_t)B_ * ND_;  // second half of d_out
  bf16_t* CTX = Kb;             // K dead after stage-1 attention

  k_cvt_w<<<1440, 256, 0, stream>>>(Wq, Wk, Wv, Wc, Wo, Wqb, Wkb, Wvb, Wcb,
                                    Wob);
  k_segmean_cvt<<<192, 256, 0, stream>>>(x, tid, Mx, Xb);
  k_gemm_plain<<<dim3(32, 6), 256, 0, stream>>>(Mx, Wcb, bc, Mx, Mb, 0, 0);
  k_gemm_plain<<<dim3(32, 6), 256, 0, stream>>>(Mb, Wqb, nullptr, nullptr, Mq,
                                                0, 0);
  k_gemm_qkv<<<2304, 256, 0, stream>>>(Xb, Wqb, Wkb, Wvb, bq, bk, bv, Qb, Kb,
                                       Vb);
  k_attn<<<dim3(4, B_ * H_), 256, 0, stream>>>(Qb, Kb, Vb, Mq, tid, VT, 1);
  k_attn<<<dim3(4, B_ * H_), 256, 0, stream>>>(Qb, Qb, VT, Mq, tid, CTX, 2);
  k_gemm_plain<<<768, 256, 0, stream>>>(CTX, Wob, bo, nullptr, d_out, 1, 1);
}